// Round 2
// baseline (8267.673 us; speedup 1.0000x reference)
//
#include <hip/hip_runtime.h>
#include <stdint.h>

typedef unsigned short u16;
typedef __bf16 bf16x8 __attribute__((ext_vector_type(8)));
typedef float f32x4 __attribute__((ext_vector_type(4)));

#define DEV static __device__ __forceinline__

DEV u16 f2bu(float f) {
    union { float f; unsigned u; } v; v.f = f;
    unsigned r = v.u + 0x7FFFu + ((v.u >> 16) & 1u);
    return (u16)(r >> 16);
}
DEV float fast_tanh(float x) {
    float e = __expf(2.f * x);
    return 1.f - __fdividef(2.f, e + 1.f);
}
DEV float fast_sig(float x) {
    return __fdividef(1.f, 1.f + __expf(-x));
}
DEV void gload_lds(const u16* g, u16* l) {
    __builtin_amdgcn_global_load_lds((const __attribute__((address_space(1))) void*)g,
                                     (__attribute__((address_space(3))) void*)l, 16, 0, 0);
}

// ---------------------------------------------------------------------------
// Generic 128x128 MFMA GEMM (prologue GEMMs), BK=32, 4 waves (2x2).
// ---------------------------------------------------------------------------
template<bool A_F32, bool B_F32, bool B_KXN, bool OUT_BF16, bool BIAS>
__global__ __launch_bounds__(256) void gemm128(
    const void* __restrict__ Ap, int lda,
    const void* __restrict__ Bp, int ldb,
    void* __restrict__ Cp, int ldc,
    const float* __restrict__ bias, int K)
{
    __shared__ u16 As[128 * 40];
    __shared__ u16 Bs[128 * 40];
    const int tid = threadIdx.x;
    const int lane = tid & 63, wave = tid >> 6;
    const int wr = wave >> 1, wc = wave & 1;
    const int m0 = blockIdx.y * 128, n0 = blockIdx.x * 128;

    f32x4 acc[4][4];
#pragma unroll
    for (int m = 0; m < 4; ++m)
#pragma unroll
        for (int n = 0; n < 4; ++n)
            acc[m][n] = (f32x4){0.f, 0.f, 0.f, 0.f};

    for (int k0 = 0; k0 < K; k0 += 32) {
        __syncthreads();
        if (A_F32) {
            const float* A = (const float*)Ap;
#pragma unroll
            for (int i = 0; i < 4; ++i) {
                int c = tid + i * 256;
                int row = c >> 3, kc = (c & 7) * 4;
                float4 v = *(const float4*)&A[(size_t)(m0 + row) * lda + k0 + kc];
                ushort4 o; o.x = f2bu(v.x); o.y = f2bu(v.y); o.z = f2bu(v.z); o.w = f2bu(v.w);
                *(ushort4*)&As[row * 40 + kc] = o;
            }
        } else {
            const u16* A = (const u16*)Ap;
#pragma unroll
            for (int i = 0; i < 2; ++i) {
                int c = tid + i * 256;
                int row = c >> 2, kc = (c & 3) * 8;
                *(int4*)&As[row * 40 + kc] = *(const int4*)&A[(size_t)(m0 + row) * lda + k0 + kc];
            }
        }
        if (B_KXN) {
            const float* B = (const float*)Bp;
#pragma unroll
            for (int i = 0; i < 4; ++i) {
                int c = tid + i * 256;
                int kk = c >> 5, nc = (c & 31) * 4;
                float4 v = *(const float4*)&B[(size_t)(k0 + kk) * ldb + n0 + nc];
                Bs[(nc + 0) * 40 + kk] = f2bu(v.x);
                Bs[(nc + 1) * 40 + kk] = f2bu(v.y);
                Bs[(nc + 2) * 40 + kk] = f2bu(v.z);
                Bs[(nc + 3) * 40 + kk] = f2bu(v.w);
            }
        } else if (B_F32) {
            const float* B = (const float*)Bp;
#pragma unroll
            for (int i = 0; i < 4; ++i) {
                int c = tid + i * 256;
                int row = c >> 3, kc = (c & 7) * 4;
                float4 v = *(const float4*)&B[(size_t)(n0 + row) * ldb + k0 + kc];
                ushort4 o; o.x = f2bu(v.x); o.y = f2bu(v.y); o.z = f2bu(v.z); o.w = f2bu(v.w);
                *(ushort4*)&Bs[row * 40 + kc] = o;
            }
        } else {
            const u16* B = (const u16*)Bp;
#pragma unroll
            for (int i = 0; i < 2; ++i) {
                int c = tid + i * 256;
                int row = c >> 2, kc = (c & 3) * 8;
                *(int4*)&Bs[row * 40 + kc] = *(const int4*)&B[(size_t)(n0 + row) * ldb + k0 + kc];
            }
        }
        __syncthreads();
        const int fr = lane & 15, kq = (lane >> 4) * 8;
        bf16x8 af[4], bq[4];
#pragma unroll
        for (int m = 0; m < 4; ++m)
            af[m] = *(const bf16x8*)&As[(wr * 64 + m * 16 + fr) * 40 + kq];
#pragma unroll
        for (int n = 0; n < 4; ++n)
            bq[n] = *(const bf16x8*)&Bs[(wc * 64 + n * 16 + fr) * 40 + kq];
#pragma unroll
        for (int m = 0; m < 4; ++m)
#pragma unroll
            for (int n = 0; n < 4; ++n)
                acc[m][n] = __builtin_amdgcn_mfma_f32_16x16x32_bf16(af[m], bq[n], acc[m][n], 0, 0, 0);
    }
    const int fr = lane & 15, rq = (lane >> 4) * 4;
#pragma unroll
    for (int m = 0; m < 4; ++m) {
#pragma unroll
        for (int n = 0; n < 4; ++n) {
            int col = n0 + wc * 64 + n * 16 + fr;
            float bv = BIAS ? bias[col] : 0.f;
#pragma unroll
            for (int r = 0; r < 4; ++r) {
                int row = m0 + wr * 64 + m * 16 + rq + r;
                float v = acc[m][n][r] + bv;
                if (OUT_BF16) ((u16*)Cp)[(size_t)row * ldc + col] = f2bu(v);
                else          ((float*)Cp)[(size_t)row * ldc + col] = v;
            }
        }
    }
}

// ---------------------------------------------------------------------------
// Head GEMM: C[2048][32000] = A(bf16 [2048][1024]) @ B(bf16 [32000][1024])^T
// m97-style: global_load_lds width-16, 128x128 tile, BK=32, XCD+m-fastest swizzle.
// ---------------------------------------------------------------------------
__global__ __launch_bounds__(256) void gemm_head(const u16* __restrict__ A,
                                                 const u16* __restrict__ B,
                                                 float* __restrict__ C)
{
    __shared__ u16 As[128 * 32];
    __shared__ u16 Bs[128 * 32];
    const int tid = threadIdx.x, lane = tid & 63, wave = tid >> 6;
    const int wr = wave >> 1, wc = wave & 1;
    int bid = blockIdx.x;                       // 4000 = 8 * 500
    int nb = (bid & 7) * 500 + (bid >> 3);      // XCD-chunked
    const int m0 = (nb & 15) * 128;             // m fastest -> B-panel L2 reuse
    const int n0 = (nb >> 4) * 128;

    f32x4 acc[4][4];
#pragma unroll
    for (int m = 0; m < 4; ++m)
#pragma unroll
        for (int n = 0; n < 4; ++n)
            acc[m][n] = (f32x4){0.f, 0.f, 0.f, 0.f};

    const int srow = lane >> 2;          // 0..15 within 16-row group
    const int sk = (lane & 3) * 8;       // elem offset within 32-elem row
    const int fr = lane & 15, kq = (lane >> 4) * 8;

    for (int k0 = 0; k0 < 1024; k0 += 32) {
        __syncthreads();
#pragma unroll
        for (int j = 0; j < 2; ++j) {
            const int rb = (j * 4 + wave) * 16;
            gload_lds(&A[(size_t)(m0 + rb + srow) * 1024 + k0 + sk], &As[rb * 32]);
            gload_lds(&B[(size_t)(n0 + rb + srow) * 1024 + k0 + sk], &Bs[rb * 32]);
        }
        __syncthreads();
        bf16x8 af[4], bq[4];
#pragma unroll
        for (int m = 0; m < 4; ++m)
            af[m] = *(const bf16x8*)&As[(wr * 64 + m * 16 + fr) * 32 + kq];
#pragma unroll
        for (int n = 0; n < 4; ++n)
            bq[n] = *(const bf16x8*)&Bs[(wc * 64 + n * 16 + fr) * 32 + kq];
#pragma unroll
        for (int m = 0; m < 4; ++m)
#pragma unroll
            for (int n = 0; n < 4; ++n)
                acc[m][n] = __builtin_amdgcn_mfma_f32_16x16x32_bf16(af[m], bq[n], acc[m][n], 0, 0, 0);
    }
    const int rq = (lane >> 4) * 4;
#pragma unroll
    for (int m = 0; m < 4; ++m)
#pragma unroll
        for (int n = 0; n < 4; ++n) {
            int col = n0 + wc * 64 + n * 16 + fr;
#pragma unroll
            for (int r = 0; r < 4; ++r)
                C[(size_t)(m0 + wr * 64 + m * 16 + rq + r) * 32000 + col] = acc[m][n][r];
        }
}

// ---------------------------------------------------------------------------
// Prologue kernels
// ---------------------------------------------------------------------------
__global__ __launch_bounds__(256) void mean_k(const float* __restrict__ img, float* __restrict__ gT)
{
    int b = blockIdx.x >> 3, ch = blockIdx.x & 7;
    int d = ch * 256 + threadIdx.x;
    float s = 0.f;
    for (int n = 0; n < 196; ++n)
        s += img[((size_t)b * 196 + n) * 2048 + d];
    gT[d * 64 + b] = s * (1.f / 196.f);
}

__global__ __launch_bounds__(256) void emb_gather(const int* __restrict__ tok,
                                                  const float* __restrict__ embed,
                                                  u16* __restrict__ emb_bf)
{
    int id = blockIdx.x * 256 + threadIdx.x;   // 2048*512
    int row = id >> 9, e = id & 511;
    int tk = tok[row];
    emb_bf[(size_t)row * 512 + e] = f2bu(embed[(size_t)tk * 512 + e]);
}

__global__ __launch_bounds__(256) void cvt_bf16(const float* __restrict__ in, u16* __restrict__ out)
{
    int i = blockIdx.x * 256 + threadIdx.x;
    float4 v = ((const float4*)in)[i];
    ushort4 o; o.x = f2bu(v.x); o.y = f2bu(v.y); o.z = f2bu(v.z); o.w = f2bu(v.w);
    ((ushort4*)out)[i] = o;
}

__global__ __launch_bounds__(256) void bias_sum(const float* __restrict__ a, const float* __restrict__ b,
                                                float* __restrict__ o)
{
    int i = blockIdx.x * 256 + threadIdx.x;
    o[i] = a[i] + b[i];
}

__global__ __launch_bounds__(256) void h0c0(const float* __restrict__ gT,
                                            const float* __restrict__ Wh0, const float* __restrict__ bh0,
                                            const float* __restrict__ Wc0, const float* __restrict__ bc0,
                                            float* __restrict__ c, u16* __restrict__ h0)
{
    int id = blockIdx.x * 256 + threadIdx.x;   // 65536
    int b = id & 63, n = id >> 6;
    const float4* Wh = (const float4*)&Wh0[(size_t)n * 2048];
    const float4* Wc = (const float4*)&Wc0[(size_t)n * 2048];
    float s0 = 0.f, s1 = 0.f;
#pragma unroll 4
    for (int k4 = 0; k4 < 512; ++k4) {
        float4 wh = Wh[k4], wc = Wc[k4];
        float g0 = gT[(k4 * 4 + 0) * 64 + b];
        float g1 = gT[(k4 * 4 + 1) * 64 + b];
        float g2 = gT[(k4 * 4 + 2) * 64 + b];
        float g3 = gT[(k4 * 4 + 3) * 64 + b];
        s0 += wh.x * g0 + wh.y * g1 + wh.z * g2 + wh.w * g3;
        s1 += wc.x * g0 + wc.y * g1 + wc.z * g2 + wc.w * g3;
    }
    c[b * 1024 + n] = fast_tanh(s1 + bc0[n]);
    h0[(size_t)b * 1024 + n] = f2bu(fast_tanh(s0 + bh0[n]));
}

// ---------------------------------------------------------------------------
// Persistent recurrence kernel: 256 blocks x 256 threads, 32 steps,
// 4 grid barriers per step.
// ---------------------------------------------------------------------------
DEV void gbar(unsigned* bar, unsigned target)
{
    __syncthreads();
    if (threadIdx.x == 0) {
        __threadfence();
        atomicAdd(bar, 1u);
        unsigned long long t0 = __builtin_amdgcn_s_memrealtime();
        while (__hip_atomic_load(bar, __ATOMIC_ACQUIRE, __HIP_MEMORY_SCOPE_AGENT) < target) {
            __builtin_amdgcn_s_sleep(2);
            if (__builtin_amdgcn_s_memrealtime() - t0 > 10000000ULL) break;  // ~100ms escape
        }
    }
    __syncthreads();
}

__global__ __launch_bounds__(256, 2) void recur(
    const u16* __restrict__ Whid_bf,   // [256][1024]
    const u16* __restrict__ Wic,       // [4096][2048]
    const u16* __restrict__ Whh_bf,    // [4096][1024]
    const float* __restrict__ proj,    // [64][196][256]
    const u16* __restrict__ img_bf,    // [64][196][2048]
    const float* __restrict__ w_score, // [256]
    const float* __restrict__ xg,      // [2048][4096]
    float* __restrict__ cbuf,          // [64][1024]
    u16* __restrict__ hbuf,            // [2][64][1024]
    u16* __restrict__ ctx_bf,          // [64][2048]
    float* __restrict__ ph_all,        // [64][256]
    float* __restrict__ probs,         // [64][200]
    u16* __restrict__ h_all,           // [2048][1024]
    unsigned* __restrict__ bar)
{
    const int bid = blockIdx.x, tid = threadIdx.x;
    const int lane = tid & 63, wave = tid >> 6;
    const int fr = lane & 15, kq = (lane >> 4) * 8, rq = (lane >> 4) * 4;
    __shared__ union {
        float ared[4][64][16];
        struct { float ph[256], ws[256], sc[256], red[256]; } b;
        struct { float sc[200]; float part[4][512]; } c;
        float dred[4][64][16];
    } sm;
    unsigned ep = 0;

    for (int t = 0; t < 32; ++t) {
        const int cur = t & 1, nxt = cur ^ 1;
        const u16* hb = hbuf + cur * 65536;

        // ---- Phase A: ph_all = h @ W_hid^T  (blocks 0..15, 16 a-cols each,
        //      4 waves K-split 256 each, LDS reduce)
        if (bid < 16) {
            const int n0a = bid * 16;
            f32x4 pac[4];
#pragma unroll
            for (int m = 0; m < 4; ++m) pac[m] = (f32x4){0.f, 0.f, 0.f, 0.f};
            for (int kk = 0; kk < 256; kk += 32) {
                const int k0 = wave * 256 + kk;
                bf16x8 bqv = *(const bf16x8*)&Whid_bf[(size_t)(n0a + fr) * 1024 + k0 + kq];
#pragma unroll
                for (int m = 0; m < 4; ++m) {
                    bf16x8 afv = *(const bf16x8*)&hb[(size_t)(m * 16 + fr) * 1024 + k0 + kq];
                    pac[m] = __builtin_amdgcn_mfma_f32_16x16x32_bf16(afv, bqv, pac[m], 0, 0, 0);
                }
            }
#pragma unroll
            for (int m = 0; m < 4; ++m)
#pragma unroll
                for (int r = 0; r < 4; ++r)
                    sm.ared[wave][m * 16 + rq + r][fr] = pac[m][r];
            __syncthreads();
#pragma unroll
            for (int i = 0; i < 4; ++i) {
                int idx = tid + i * 256;
                int bb = idx >> 4, col = idx & 15;
                ph_all[bb * 256 + n0a + col] =
                    sm.ared[0][bb][col] + sm.ared[1][bb][col] + sm.ared[2][bb][col] + sm.ared[3][bb][col];
            }
        }
        gbar(bar, ++ep * 256u);

        // ---- Phase B: scores + softmax (blocks 0..63, one per batch)
        if (bid < 64) {
            const int b = bid;
            sm.b.ph[tid] = ph_all[b * 256 + tid];
            sm.b.ws[tid] = w_score[tid];
            sm.b.sc[tid] = -1e30f;
            __syncthreads();
            for (int n = wave; n < 196; n += 4) {
                const int a0 = lane * 4;
                float4 p = *(const float4*)&proj[((size_t)b * 196 + n) * 256 + a0];
                float s = sm.b.ws[a0 + 0] * fast_tanh(p.x + sm.b.ph[a0 + 0])
                        + sm.b.ws[a0 + 1] * fast_tanh(p.y + sm.b.ph[a0 + 1])
                        + sm.b.ws[a0 + 2] * fast_tanh(p.z + sm.b.ph[a0 + 2])
                        + sm.b.ws[a0 + 3] * fast_tanh(p.w + sm.b.ph[a0 + 3]);
#pragma unroll
                for (int off = 32; off; off >>= 1) s += __shfl_xor(s, off, 64);
                if (lane == 0) sm.b.sc[n] = s;
            }
            __syncthreads();
            sm.b.red[tid] = sm.b.sc[tid];
            __syncthreads();
#pragma unroll
            for (int s2 = 128; s2 > 0; s2 >>= 1) {
                if (tid < s2) sm.b.red[tid] = fmaxf(sm.b.red[tid], sm.b.red[tid + s2]);
                __syncthreads();
            }
            const float mx = sm.b.red[0];
            __syncthreads();
            float e = (tid < 196) ? __expf(sm.b.sc[tid] - mx) : 0.f;
            sm.b.red[tid] = e;
            __syncthreads();
#pragma unroll
            for (int s2 = 128; s2 > 0; s2 >>= 1) {
                if (tid < s2) sm.b.red[tid] += sm.b.red[tid + s2];
                __syncthreads();
            }
            if (tid < 196) probs[b * 200 + tid] = e * __fdividef(1.f, sm.b.red[0]);
        }
        gbar(bar, ++ep * 256u);

        // ---- Phase C: ctx (all 256 blocks: b = bid>>2, d-quarter = bid&3)
        {
            const int b = bid >> 2, q = bid & 3;
            if (tid < 196) sm.c.sc[tid] = probs[b * 200 + tid];
            __syncthreads();
            const int gid = tid >> 2, st = tid & 3;
            const int c0 = q * 512 + gid * 8;
            const u16* base = img_bf + ((size_t)b * 196) * 2048 + c0;
            float a[8];
#pragma unroll
            for (int i = 0; i < 8; ++i) a[i] = 0.f;
            for (int n = st; n < 196; n += 4) {
                bf16x8 v = *(const bf16x8*)(base + (size_t)n * 2048);
                float w = sm.c.sc[n];
#pragma unroll
                for (int i = 0; i < 8; ++i) a[i] += w * (float)v[i];
            }
#pragma unroll
            for (int i = 0; i < 8; ++i) sm.c.part[st][gid * 8 + i] = a[i];
            __syncthreads();
            const int col = tid * 2;
            float v0 = sm.c.part[0][col] + sm.c.part[1][col] + sm.c.part[2][col] + sm.c.part[3][col];
            float v1 = sm.c.part[0][col + 1] + sm.c.part[1][col + 1] + sm.c.part[2][col + 1] + sm.c.part[3][col + 1];
            ushort2 o; o.x = f2bu(v0); o.y = f2bu(v1);
            *(ushort2*)&ctx_bf[(size_t)b * 2048 + q * 512 + col] = o;
        }
        gbar(bar, ++ep * 256u);

        // ---- Phase D: gates + LSTM pointwise (all 256 blocks, 4 hidden cols each,
        //      4 waves K-split 768, LDS reduce)
        {
            const int hc0 = bid * 4;
            const int grow = (fr >> 2) * 1024 + hc0 + (fr & 3);
            const u16* WicR = Wic + (size_t)grow * 2048;
            const u16* WhhR = Whh_bf + (size_t)grow * 1024;
            f32x4 dacc[4];
#pragma unroll
            for (int m = 0; m < 4; ++m) dacc[m] = (f32x4){0.f, 0.f, 0.f, 0.f};
            for (int kk = 0; kk < 768; kk += 32) {
                const int k0 = wave * 768 + kk;
                if (k0 < 2048) {
                    bf16x8 bqv = *(const bf16x8*)&WicR[k0 + kq];
#pragma unroll
                    for (int m = 0; m < 4; ++m) {
                        bf16x8 afv = *(const bf16x8*)&ctx_bf[(size_t)(m * 16 + fr) * 2048 + k0 + kq];
                        dacc[m] = __builtin_amdgcn_mfma_f32_16x16x32_bf16(afv, bqv, dacc[m], 0, 0, 0);
                    }
                } else {
                    const int kh = k0 - 2048;
                    bf16x8 bqv = *(const bf16x8*)&WhhR[kh + kq];
#pragma unroll
                    for (int m = 0; m < 4; ++m) {
                        bf16x8 afv = *(const bf16x8*)&hb[(size_t)(m * 16 + fr) * 1024 + kh + kq];
                        dacc[m] = __builtin_amdgcn_mfma_f32_16x16x32_bf16(afv, bqv, dacc[m], 0, 0, 0);
                    }
                }
            }
#pragma unroll
            for (int m = 0; m < 4; ++m)
#pragma unroll
                for (int r = 0; r < 4; ++r)
                    sm.dred[wave][m * 16 + rq + r][fr] = dacc[m][r];
            __syncthreads();
            {
                const int bb = tid >> 2, j = tid & 3;
                float G[4];
#pragma unroll
                for (int g = 0; g < 4; ++g) {
                    const int f2 = g * 4 + j;
                    G[g] = sm.dred[0][bb][f2] + sm.dred[1][bb][f2] + sm.dred[2][bb][f2] + sm.dred[3][bb][f2]
                         + xg[((size_t)bb * 32 + t) * 4096 + g * 1024 + hc0 + j];
                }
                float ig = fast_sig(G[0]), fg = fast_sig(G[1]);
                float gv = fast_tanh(G[2]), og = fast_sig(G[3]);
                const int col = hc0 + j;
                float cp = cbuf[bb * 1024 + col];
                float cn = fg * cp + ig * gv;
                cbuf[bb * 1024 + col] = cn;
                u16 hv = f2bu(og * fast_tanh(cn));
                hbuf[nxt * 65536 + bb * 1024 + col] = hv;
                h_all[((size_t)bb * 32 + t) * 1024 + col] = hv;
            }
        }
        gbar(bar, ++ep * 256u);
    }
}

// ---------------------------------------------------------------------------
extern "C" void kernel_launch(void* const* d_in, const int* in_sizes, int n_in,
                              void* d_out, int out_size, void* d_ws, size_t ws_size,
                              hipStream_t stream)
{
    const float* img     = (const float*)d_in[0];   // [64][196][2048]
    const int*   tok     = (const int*)d_in[1];     // [64][32]
    const float* embed   = (const float*)d_in[2];   // [32000][512]
    const float* W_head1 = (const float*)d_in[3];   // [512][2560]
    const float* W_ih    = (const float*)d_in[4];   // [4096][512]
    const float* W_hh    = (const float*)d_in[5];   // [4096][1024]
    const float* b_ih    = (const float*)d_in[6];   // [4096]
    const float* b_hh    = (const float*)d_in[7];   // [4096]
    const float* W_head  = (const float*)d_in[8];   // [32000][1024]
    const float* W_img   = (const float*)d_in[9];   // [256][2048]
    const float* W_hid   = (const float*)d_in[10];  // [256][1024]
    const float* w_score = (const float*)d_in[11];  // [256]
    const float* W_h0    = (const float*)d_in[12];  // [1024][2048]
    const float* b_h0    = (const float*)d_in[13];  // [1024]
    const float* W_c0    = (const float*)d_in[14];  // [1024][2048]
    const float* b_c0    = (const float*)d_in[15];  // [1024]
    float* out = (float*)d_out;                     // [64][32][32000]

    char* w = (char*)d_ws;
    size_t off = 0;
    auto alloc = [&](size_t bytes) { char* p = w + off; off += (bytes + 255) & ~(size_t)255; return p; };

    u16*   Wic      = (u16*)alloc(4096ULL * 2048 * 2);
    u16*   Whh_bf   = (u16*)alloc(4096ULL * 1024 * 2);
    u16*   Whid_bf  = (u16*)alloc(256ULL * 1024 * 2);
    u16*   Whead_bf = (u16*)alloc(32000ULL * 1024 * 2);
    u16*   img_bf   = (u16*)alloc(64ULL * 196 * 2048 * 2);
    float* xg       = (float*)alloc(2048ULL * 4096 * 4);
    float* proj     = (float*)alloc(64ULL * 196 * 256 * 4);
    u16*   emb_bf   = (u16*)alloc(2048ULL * 512 * 2);
    u16*   xe       = (u16*)alloc(2048ULL * 512 * 2);
    float* gT       = (float*)alloc(2048ULL * 64 * 4);
    float* cbuf     = (float*)alloc(64ULL * 1024 * 4);
    u16*   hbuf     = (u16*)alloc(2ULL * 64 * 1024 * 2);
    u16*   ctx_bf   = (u16*)alloc(64ULL * 2048 * 2);
    u16*   h_all    = (u16*)alloc(2048ULL * 1024 * 2);
    float* ph_all   = (float*)alloc(64ULL * 256 * 4);
    float* probs    = (float*)alloc(64ULL * 200 * 4);
    float* bsum     = (float*)alloc(4096ULL * 4);
    unsigned* bar   = (unsigned*)alloc(256);
    (void)ws_size; (void)in_sizes; (void)n_in; (void)out_size;

    // ---- prologue
    mean_k<<<dim3(512), dim3(256), 0, stream>>>(img, gT);
    emb_gather<<<dim3(4096), dim3(256), 0, stream>>>(tok, embed, emb_bf);
    cvt_bf16<<<dim3(4096), dim3(256), 0, stream>>>(W_hh, Whh_bf);      // 4.19M elems
    cvt_bf16<<<dim3(256), dim3(256), 0, stream>>>(W_hid, Whid_bf);     // 262K
    cvt_bf16<<<dim3(32000), dim3(256), 0, stream>>>(W_head, Whead_bf); // 32.77M
    cvt_bf16<<<dim3(25088), dim3(256), 0, stream>>>(img, img_bf);      // 25.69M
    bias_sum<<<dim3(16), dim3(256), 0, stream>>>(b_ih, b_hh, bsum);
    h0c0<<<dim3(256), dim3(256), 0, stream>>>(gT, W_h0, b_h0, W_c0, b_c0, cbuf, hbuf);

    // xe = emb @ Wa^T  (Wa = W_head1[:, :512])
    gemm128<false, true, false, true, false><<<dim3(4, 16), dim3(256), 0, stream>>>(
        emb_bf, 512, W_head1, 2560, xe, 512, nullptr, 512);
    // xg = xe @ W_ih^T + (b_ih + b_hh)
    gemm128<false, true, false, false, true><<<dim3(32, 16), dim3(256), 0, stream>>>(
        xe, 512, W_ih, 512, xg, 4096, bsum, 512);
    // Wic = W_ih @ W_head1[:, 512:]
    gemm128<true, true, true, true, false><<<dim3(16, 32), dim3(256), 0, stream>>>(
        W_ih, 512, W_head1 + 512, 2560, Wic, 2048, nullptr, 512);
    // proj = img @ W_img^T
    gemm128<true, true, false, false, false><<<dim3(2, 98), dim3(256), 0, stream>>>(
        img, 2048, W_img, 2048, proj, 256, nullptr, 2048);

    // ---- recurrence (persistent, 128 grid barriers)
    hipMemsetAsync(bar, 0, 256, stream);
    recur<<<dim3(256), dim3(256), 0, stream>>>(Whid_bf, Wic, Whh_bf, proj, img_bf,
                                               w_score, xg, cbuf, hbuf, ctx_bf,
                                               ph_all, probs, h_all, bar);

    // ---- logits: out = h_all @ W_head^T
    gemm_head<<<dim3(4000), dim3(256), 0, stream>>>(h_all, Whead_bf, out);
}